// Round 2
// baseline (9882.013 us; speedup 1.0000x reference)
//
#include <hip/hip_runtime.h>

// C4Transformer forward, MI355X. Round 1: ALL-f32 pipeline (correctness isolation).
// Key insight: q>0 branch + global top-32 selection are discrete; everything feeding
// them (i.e. all of layer 0/1 up to the last q/k use) must be f32-grade, or bf16
// noise cascades into sign flips with O(0.05) output jumps.

#define NTOK 262144
#define LOG2E 1.44269504088896340736f

// ---------------- embed: x = byte_embed[bytes] + block_pos + local_pos ----------------
__global__ __launch_bounds__(256) void embed_kernel(const int* __restrict__ bytes,
    const float* __restrict__ be, const float* __restrict__ bpe,
    const float* __restrict__ lpe, float* __restrict__ x)
{
  int i4 = blockIdx.x * 256 + threadIdx.x;   // grid 32768: one float4 per thread
  int n  = i4 >> 5;
  int dq = (i4 & 31) * 4;
  int b  = bytes[n];
  float4 a = *(const float4*)(be  + b * 128 + dq);
  float4 c = *(const float4*)(bpe + (n >> 8) * 128 + dq);
  float4 d = *(const float4*)(lpe + (n & 255) * 128 + dq);
  float4 o;
  o.x = (a.x + c.x) + d.x; o.y = (a.y + c.y) + d.y;
  o.z = (a.z + c.z) + d.z; o.w = (a.w + c.w) + d.w;
  *(float4*)(x + (size_t)n * 128 + dq) = o;
}

// ---------------- per-token rms scale: s[tok] = rsqrt(mean(x^2)+eps), Newton-refined --
__global__ __launch_bounds__(256) void scale_kernel(const float* __restrict__ x,
    float* __restrict__ s)
{
  const int lane = threadIdx.x & 63;
  const int gw = blockIdx.x * 4 + (threadIdx.x >> 6);   // grid 1024 -> 4096 waves
  for (int tok = gw; tok < NTOK; tok += 4096) {
    const float2 v = *(const float2*)&x[(size_t)tok * 128 + lane * 2];
    float ss = v.x * v.x + v.y * v.y;
    #pragma unroll
    for (int off = 1; off < 64; off <<= 1) ss += __shfl_xor(ss, off, 64);
    const float m = ss * (1.f / 128.f) + 1.1920929e-07f;
    float r = rsqrtf(m);
    r = r * (1.5f - 0.5f * m * r * r);   // 1 Newton step -> ~1 ulp
    if (lane == 0) s[tok] = r;
  }
}

// ---------------- f32 GEMM: C[M][N] = (A .* rs .* cw)[M][K] * B[N][K]^T ----------------
// tile 64 tok x 128 col, K chunks of 64, LDS transposed [k][tok]/[k][col].
// 4-term grouped accumulation: acc-scale roundings only every 4 terms (~np pairwise err).
enum { M32_QK = 0, M32_RESID = 1, M32_RAW = 2 };

template<int MODE>
__global__ __launch_bounds__(256) void gemm_f32(
    const float* __restrict__ A, const float* __restrict__ rs, const float* __restrict__ cw,
    const float* __restrict__ B, const float* __restrict__ Bb,
    int K, int ldb, int Brows, int Bkcols,
    float* __restrict__ O, float* __restrict__ O2, int ldo)
{
  __shared__ float La[64][68];    // [k][tok]
  __shared__ float Lb[64][132];   // [k][col]
  __shared__ float cwS[128];      // norm col-weights (only K=128 modes use cw)
  const int t = threadIdx.x;
  const int m0 = blockIdx.x * 64;
  const int n0 = (MODE == M32_QK) ? 0 : blockIdx.y * 128;
  const float* Bu = (MODE == M32_QK && blockIdx.y) ? Bb : B;
  for (int i = t; i < 128; i += 256) cwS[i] = cw ? cw[i] : 1.f;
  __syncthreads();

  float acc[4][8] = {};
  const int ta = (t & 15) * 4;    // token sub-offset
  const int tb = (t >> 4) * 8;    // col sub-offset

  for (int k0 = 0; k0 < K; k0 += 64) {
    for (int c = t; c < 1024; c += 256) {          // A: 64 tok x 64 k
      int tok = c >> 4, k4 = (c & 15) * 4;
      float4 av = *(const float4*)&A[(size_t)(m0 + tok) * K + k0 + k4];
      float rsv = rs ? rs[m0 + tok] : 1.f;
      La[k4 + 0][tok] = av.x * rsv * cwS[(k0 + k4 + 0) & 127];
      La[k4 + 1][tok] = av.y * rsv * cwS[(k0 + k4 + 1) & 127];
      La[k4 + 2][tok] = av.z * rsv * cwS[(k0 + k4 + 2) & 127];
      La[k4 + 3][tok] = av.w * rsv * cwS[(k0 + k4 + 3) & 127];
    }
    for (int c = t; c < 2048; c += 256) {          // B: 128 col x 64 k, zero-padded
      int col = c >> 4, k4 = (c & 15) * 4;
      int gr = n0 + col;
      float4 bv = make_float4(0.f, 0.f, 0.f, 0.f);
      if (gr < Brows) {
        int kb = k0 + k4;
        if (((ldb & 3) == 0) && kb + 3 < Bkcols) {
          bv = *(const float4*)&Bu[(size_t)gr * ldb + kb];
        } else {
          float* bp = (float*)&bv;
          #pragma unroll
          for (int j = 0; j < 4; j++)
            if (kb + j < Bkcols) bp[j] = Bu[(size_t)gr * ldb + kb + j];
        }
      }
      Lb[k4 + 0][col] = bv.x; Lb[k4 + 1][col] = bv.y;
      Lb[k4 + 2][col] = bv.z; Lb[k4 + 3][col] = bv.w;
    }
    __syncthreads();
    for (int kq = 0; kq < 64; kq += 4) {
      float aa[4][4], bb[4][8];
      #pragma unroll
      for (int kk = 0; kk < 4; kk++) {
        *(float4*)&aa[kk][0] = *(const float4*)&La[kq + kk][ta];
        *(float4*)&bb[kk][0] = *(const float4*)&Lb[kq + kk][tb];
        *(float4*)&bb[kk][4] = *(const float4*)&Lb[kq + kk][tb + 4];
      }
      #pragma unroll
      for (int i = 0; i < 4; i++)
        #pragma unroll
        for (int j = 0; j < 8; j++) {
          float tt = aa[0][i] * bb[0][j];
          tt = fmaf(aa[1][i], bb[1][j], tt);
          tt = fmaf(aa[2][i], bb[2][j], tt);
          tt = fmaf(aa[3][i], bb[3][j], tt);
          acc[i][j] += tt;
        }
    }
    __syncthreads();
  }

  if (MODE == M32_QK) {
    if (blockIdx.y == 0) {               // q row-major [tok][128]
      #pragma unroll
      for (int i = 0; i < 4; i++)
        #pragma unroll
        for (int j = 0; j < 8; j++)
          O[(size_t)(m0 + ta + i) * 128 + tb + j] = acc[i][j];
    } else {                             // kt transposed [head][tok]
      #pragma unroll
      for (int i = 0; i < 4; i++)
        #pragma unroll
        for (int j = 0; j < 8; j++)
          O2[(size_t)(tb + j) * NTOK + (m0 + ta + i)] = acc[i][j];
    }
  } else if (MODE == M32_RESID) {        // x += acc
    #pragma unroll
    for (int i = 0; i < 4; i++)
      #pragma unroll
      for (int j = 0; j < 8; j++) {
        size_t ix = (size_t)(m0 + ta + i) * ldo + n0 + tb + j;
        O[ix] += acc[i][j];
      }
  } else {                               // raw store
    #pragma unroll
    for (int i = 0; i < 4; i++)
      #pragma unroll
      for (int j = 0; j < 8; j++)
        O[(size_t)(m0 + ta + i) * ldo + n0 + tb + j] = acc[i][j];
  }
}

// ---------------- per-head top/bot-32 selection + exact tabV dot ----------------
// grid 256: blockIdx = head*2 + (0=top,1=bot). tabK pre-scaled by log2(e).
// tabV[slot][h] = dot(x[idx] .* n1w, Wv[h]) * s[idx]  (recomputed, no v buffer).
__global__ __launch_bounds__(128) void sel_kernel(const float* __restrict__ kt,
    const float* __restrict__ x, const float* __restrict__ s, const float* __restrict__ nw,
    const float* __restrict__ Wv, float* __restrict__ tabK, float* __restrict__ tabV)
{
  __shared__ float tvS[128 * 33];
  __shared__ int   tiS[128 * 33];
  __shared__ float red[128];
  __shared__ int   redi[128];
  __shared__ float selv[32];
  __shared__ int   seli[32];
  const int t = threadIdx.x;
  const int h = blockIdx.x >> 1;
  const int sb = blockIdx.x & 1;
  const float sgn = sb ? -1.f : 1.f;
  float* mv = &tvS[t * 33];
  int*   mi = &tiS[t * 33];
  int cnt = 0;
  const float* row = kt + (size_t)h * NTOK;
  for (int i = t; i < NTOK; i += 128) {
    float val = sgn * row[i];
    if (cnt == 32) {
      if (val <= mv[0]) continue;
      int p = 1;
      for (; p < 32 && mv[p] < val; p++) { mv[p - 1] = mv[p]; mi[p - 1] = mi[p]; }
      mv[p - 1] = val; mi[p - 1] = i;
    } else {
      int p = cnt;
      for (; p > 0 && mv[p - 1] > val; p--) { mv[p] = mv[p - 1]; mi[p] = mi[p - 1]; }
      mv[p] = val; mi[p] = i; cnt++;
    }
  }
  __syncthreads();
  for (int e = 0; e < 32; e++) {
    red[t]  = cnt ? mv[cnt - 1] : -3.4e38f;
    redi[t] = t;
    __syncthreads();
    for (int off = 64; off > 0; off >>= 1) {
      if (t < off && red[t + off] > red[t]) { red[t] = red[t + off]; redi[t] = redi[t + off]; }
      __syncthreads();
    }
    if (t == redi[0]) { selv[e] = mv[cnt - 1]; seli[e] = mi[cnt - 1]; cnt--; }
    __syncthreads();
  }
  if (t < 32) {
    float kval = sgn * selv[t];
    int idx = seli[t];
    tabK[(sb * 32 + t) * 128 + h] = kval * LOG2E;
    float acc = 0.f;
    const float* xr = &x[(size_t)idx * 128];
    const float* wv = &Wv[h * 128];
    for (int k = 0; k < 128; k++) acc = fmaf(xr[k] * nw[k], wv[k], acc);
    tabV[(sb * 32 + t) * 128 + h] = acc * s[idx];
  }
}

// ---------------- attention: in-place q[tok][h] -> softmax(q*k_sel).v_sel ----------------
__global__ __launch_bounds__(256) void att_kernel(float* __restrict__ q,
    const float* __restrict__ tabK, const float* __restrict__ tabV)
{
  __shared__ float tk[8192];
  __shared__ float tv[8192];
  const int t = threadIdx.x;
  for (int i = t; i < 8192; i += 256) { tk[i] = tabK[i]; tv[i] = tabV[i]; }
  __syncthreads();
  const int h = t & 127;
  const int base = blockIdx.x * 128;   // grid 2048
  for (int it = 0; it < 64; it++) {
    const int tok = base + it * 2 + (t >> 7);
    const size_t off = (size_t)tok * 128 + h;
    const float qv = q[off];
    const int b = (qv > 0.f) ? 0 : 4096;   // q==0 -> bottom, matches (q>0) in ref
    const float* kk = &tk[b + h];
    const float* vv = &tv[b + h];
    float sw = 0.f, swv = 0.f;
    #pragma unroll
    for (int j = 0; j < 32; j++) {
      float e = exp2f(qv * kk[j * 128]);
      sw += e;
      swv = fmaf(e, vv[j * 128], swv);
    }
    q[off] = swv / sw;
  }
}

// ---------------- silu-mul: g = silu(g) * u (f32, in-place over g) ----------------
__global__ __launch_bounds__(256) void silu_kernel(float* __restrict__ g,
    const float* __restrict__ u, int n4)
{
  int idx = blockIdx.x * 256 + threadIdx.x;
  for (int i = idx; i < n4; i += gridDim.x * 256) {
    float4 gv = *(float4*)&g[(size_t)i * 4];
    float4 uv = *(const float4*)&u[(size_t)i * 4];
    float4 o;
    o.x = gv.x / (1.f + expf(-gv.x)) * uv.x;
    o.y = gv.y / (1.f + expf(-gv.y)) * uv.y;
    o.z = gv.z / (1.f + expf(-gv.z)) * uv.z;
    o.w = gv.w / (1.f + expf(-gv.w)) * uv.w;
    *(float4*)&g[(size_t)i * 4] = o;
  }
}

// ---------------- host orchestration ----------------
// ws layout (bytes):
//   [0, 134217728)           x    f32 residual
//   [134217728, 268435456)   q    f32 (att writes in-place; then Wo input)
//   [268435456, 402653184)   kt   f32 [head][tok]; aliased by g/u chunks during MLP
//   [402653184, 403701760)   s    f32 per-token rms scales
//   [403701760, 403734528)   tabK f32
//   [403734528, 403767296)   tabV f32
// total ~403.8 MB (same footprint class as round 0, which ran).

extern "C" void kernel_launch(void* const* d_in, const int* in_sizes, int n_in,
                              void* d_out, int out_size, void* d_ws, size_t ws_size,
                              hipStream_t stream)
{
  (void)in_sizes; (void)n_in; (void)out_size; (void)ws_size;
  const int*   bytes = (const int*)d_in[0];
  const float* be    = (const float*)d_in[1];
  const float* bpe   = (const float*)d_in[2];
  const float* lpe   = (const float*)d_in[3];
  const float* Wq    = (const float*)d_in[4];
  const float* Wk    = (const float*)d_in[5];
  const float* Wv    = (const float*)d_in[6];
  const float* Wo    = (const float*)d_in[7];
  const float* n1w   = (const float*)d_in[8];
  const float* n2w   = (const float*)d_in[9];
  const float* wg    = (const float*)d_in[10];
  const float* wu    = (const float*)d_in[11];
  const float* wd    = (const float*)d_in[12];
  const float* fnw   = (const float*)d_in[13];
  const float* outw  = (const float*)d_in[14];
  float* out = (float*)d_out;

  char* ws = (char*)d_ws;
  float* x    = (float*)(ws + 0);
  float* q    = (float*)(ws + 134217728);
  float* kt   = (float*)(ws + 268435456);
  float* s    = (float*)(ws + 402653184);
  float* tabK = (float*)(ws + 403701760);
  float* tabV = (float*)(ws + 403734528);
  float* gbuf = kt;                       // MLP chunk scratch aliases kt
  float* ubuf = kt + 12582912;            // +48 MB (32768*384 floats)

  embed_kernel<<<32768, 256, 0, stream>>>(bytes, be, bpe, lpe, x);

  for (int l = 0; l < 2; l++) {
    const float* wq = Wq + l * 16384;
    const float* wk = Wk + l * 16384;
    const float* wv = Wv + l * 16384;
    const float* wo = Wo + l * 16384;
    const float* g1 = n1w + l * 128;
    const float* g2 = n2w + l * 128;
    const float* wgl = wg + l * 43648;
    const float* wul = wu + l * 43648;
    const float* wdl = wd + l * 43648;

    scale_kernel<<<1024, 256, 0, stream>>>(x, s);
    gemm_f32<M32_QK><<<dim3(4096, 2), 256, 0, stream>>>(
        x, s, g1, wq, wk, 128, 128, 128, 128, q, kt, 128);
    sel_kernel<<<256, 128, 0, stream>>>(kt, x, s, g1, wv, tabK, tabV);
    att_kernel<<<2048, 256, 0, stream>>>(q, tabK, tabV);
    gemm_f32<M32_RESID><<<dim3(4096, 1), 256, 0, stream>>>(
        q, nullptr, nullptr, wo, nullptr, 128, 128, 128, 128, x, nullptr, 128);

    scale_kernel<<<1024, 256, 0, stream>>>(x, s);
    for (int c = 0; c < 8; c++) {
      const size_t base = (size_t)c * 32768;
      gemm_f32<M32_RAW><<<dim3(512, 3), 256, 0, stream>>>(
          x + base * 128, s + base, g2, wgl, nullptr, 128, 128, 341, 128,
          gbuf, nullptr, 384);
      gemm_f32<M32_RAW><<<dim3(512, 3), 256, 0, stream>>>(
          x + base * 128, s + base, g2, wul, nullptr, 128, 128, 341, 128,
          ubuf, nullptr, 384);
      silu_kernel<<<3072, 256, 0, stream>>>(gbuf, ubuf, 3145728);
      gemm_f32<M32_RESID><<<dim3(512, 1), 256, 0, stream>>>(
          gbuf, nullptr, nullptr, wdl, nullptr, 384, 341, 128, 341,
          x + base * 128, nullptr, 128);
    }
  }

  scale_kernel<<<1024, 256, 0, stream>>>(x, s);
  gemm_f32<M32_RAW><<<dim3(4096, 2), 256, 0, stream>>>(
      x, s, fnw, outw, nullptr, 128, 128, 256, 128, out, nullptr, 256);
}

// Round 3
// 6285.139 us; speedup vs baseline: 1.5723x; 1.5723x over previous
//
#include <hip/hip_runtime.h>

// C4Transformer forward, MI355X. Round 2: identical arithmetic to round 1 (which
// passed at absmax 2.44e-2 with only 8e-4 margin), but the serial sel_kernel
// (2 x 2067 us = 42% of runtime) is replaced by a two-pass parallel top-k that
// produces the exact same selected set, order, and tabK/tabV values.

#define NTOK 262144
#define LOG2E 1.44269504088896340736f
#define NEGINF (-3.402823466e38f)

// ---------------- embed: x = byte_embed[bytes] + block_pos + local_pos ----------------
__global__ __launch_bounds__(256) void embed_kernel(const int* __restrict__ bytes,
    const float* __restrict__ be, const float* __restrict__ bpe,
    const float* __restrict__ lpe, float* __restrict__ x)
{
  int i4 = blockIdx.x * 256 + threadIdx.x;   // grid 32768: one float4 per thread
  int n  = i4 >> 5;
  int dq = (i4 & 31) * 4;
  int b  = bytes[n];
  float4 a = *(const float4*)(be  + b * 128 + dq);
  float4 c = *(const float4*)(bpe + (n >> 8) * 128 + dq);
  float4 d = *(const float4*)(lpe + (n & 255) * 128 + dq);
  float4 o;
  o.x = (a.x + c.x) + d.x; o.y = (a.y + c.y) + d.y;
  o.z = (a.z + c.z) + d.z; o.w = (a.w + c.w) + d.w;
  *(float4*)(x + (size_t)n * 128 + dq) = o;
}

// ---------------- per-token rms scale: s[tok] = rsqrt(mean(x^2)+eps), Newton-refined --
__global__ __launch_bounds__(256) void scale_kernel(const float* __restrict__ x,
    float* __restrict__ s)
{
  const int lane = threadIdx.x & 63;
  const int gw = blockIdx.x * 4 + (threadIdx.x >> 6);   // grid 1024 -> 4096 waves
  for (int tok = gw; tok < NTOK; tok += 4096) {
    const float2 v = *(const float2*)&x[(size_t)tok * 128 + lane * 2];
    float ss = v.x * v.x + v.y * v.y;
    #pragma unroll
    for (int off = 1; off < 64; off <<= 1) ss += __shfl_xor(ss, off, 64);
    const float m = ss * (1.f / 128.f) + 1.1920929e-07f;
    float r = rsqrtf(m);
    r = r * (1.5f - 0.5f * m * r * r);   // 1 Newton step -> ~1 ulp
    if (lane == 0) s[tok] = r;
  }
}

// ---------------- f32 GEMM: C[M][N] = (A .* rs .* cw)[M][K] * B[N][K]^T ----------------
// UNCHANGED from round 1 (arithmetic must stay bit-identical).
enum { M32_QK = 0, M32_RESID = 1, M32_RAW = 2 };

template<int MODE>
__global__ __launch_bounds__(256) void gemm_f32(
    const float* __restrict__ A, const float* __restrict__ rs, const float* __restrict__ cw,
    const float* __restrict__ B, const float* __restrict__ Bb,
    int K, int ldb, int Brows, int Bkcols,
    float* __restrict__ O, float* __restrict__ O2, int ldo)
{
  __shared__ float La[64][68];    // [k][tok]
  __shared__ float Lb[64][132];   // [k][col]
  __shared__ float cwS[128];
  const int t = threadIdx.x;
  const int m0 = blockIdx.x * 64;
  const int n0 = (MODE == M32_QK) ? 0 : blockIdx.y * 128;
  const float* Bu = (MODE == M32_QK && blockIdx.y) ? Bb : B;
  for (int i = t; i < 128; i += 256) cwS[i] = cw ? cw[i] : 1.f;
  __syncthreads();

  float acc[4][8] = {};
  const int ta = (t & 15) * 4;
  const int tb = (t >> 4) * 8;

  for (int k0 = 0; k0 < K; k0 += 64) {
    for (int c = t; c < 1024; c += 256) {
      int tok = c >> 4, k4 = (c & 15) * 4;
      float4 av = *(const float4*)&A[(size_t)(m0 + tok) * K + k0 + k4];
      float rsv = rs ? rs[m0 + tok] : 1.f;
      La[k4 + 0][tok] = av.x * rsv * cwS[(k0 + k4 + 0) & 127];
      La[k4 + 1][tok] = av.y * rsv * cwS[(k0 + k4 + 1) & 127];
      La[k4 + 2][tok] = av.z * rsv * cwS[(k0 + k4 + 2) & 127];
      La[k4 + 3][tok] = av.w * rsv * cwS[(k0 + k4 + 3) & 127];
    }
    for (int c = t; c < 2048; c += 256) {
      int col = c >> 4, k4 = (c & 15) * 4;
      int gr = n0 + col;
      float4 bv = make_float4(0.f, 0.f, 0.f, 0.f);
      if (gr < Brows) {
        int kb = k0 + k4;
        if (((ldb & 3) == 0) && kb + 3 < Bkcols) {
          bv = *(const float4*)&Bu[(size_t)gr * ldb + kb];
        } else {
          float* bp = (float*)&bv;
          #pragma unroll
          for (int j = 0; j < 4; j++)
            if (kb + j < Bkcols) bp[j] = Bu[(size_t)gr * ldb + kb + j];
        }
      }
      Lb[k4 + 0][col] = bv.x; Lb[k4 + 1][col] = bv.y;
      Lb[k4 + 2][col] = bv.z; Lb[k4 + 3][col] = bv.w;
    }
    __syncthreads();
    for (int kq = 0; kq < 64; kq += 4) {
      float aa[4][4], bb[4][8];
      #pragma unroll
      for (int kk = 0; kk < 4; kk++) {
        *(float4*)&aa[kk][0] = *(const float4*)&La[kq + kk][ta];
        *(float4*)&bb[kk][0] = *(const float4*)&Lb[kq + kk][tb];
        *(float4*)&bb[kk][4] = *(const float4*)&Lb[kq + kk][tb + 4];
      }
      #pragma unroll
      for (int i = 0; i < 4; i++)
        #pragma unroll
        for (int j = 0; j < 8; j++) {
          float tt = aa[0][i] * bb[0][j];
          tt = fmaf(aa[1][i], bb[1][j], tt);
          tt = fmaf(aa[2][i], bb[2][j], tt);
          tt = fmaf(aa[3][i], bb[3][j], tt);
          acc[i][j] += tt;
        }
    }
    __syncthreads();
  }

  if (MODE == M32_QK) {
    if (blockIdx.y == 0) {
      #pragma unroll
      for (int i = 0; i < 4; i++)
        #pragma unroll
        for (int j = 0; j < 8; j++)
          O[(size_t)(m0 + ta + i) * 128 + tb + j] = acc[i][j];
    } else {
      #pragma unroll
      for (int i = 0; i < 4; i++)
        #pragma unroll
        for (int j = 0; j < 8; j++)
          O2[(size_t)(tb + j) * NTOK + (m0 + ta + i)] = acc[i][j];
    }
  } else if (MODE == M32_RESID) {
    #pragma unroll
    for (int i = 0; i < 4; i++)
      #pragma unroll
      for (int j = 0; j < 8; j++) {
        size_t ix = (size_t)(m0 + ta + i) * ldo + n0 + tb + j;
        O[ix] += acc[i][j];
      }
  } else {
    #pragma unroll
    for (int i = 0; i < 4; i++)
      #pragma unroll
      for (int j = 0; j < 8; j++)
        O[(size_t)(m0 + ta + i) * ldo + n0 + tb + j] = acc[i][j];
  }
}

// ---------------- selection pass 1: per-wave top-32 over 2048-token slices ----------
// grid dim3(32 chunks, 256 head-branch), 256 threads (4 waves). Each wave owns 2048
// consecutive tokens; per-lane 32 values live in registers (static indexing), a u32
// bitmask marks consumed elements. 32 rounds of 64-lane shfl-butterfly argmax.
// Writes 32 (val, idx) candidates per wave -> 4096 candidates per (h, branch).
__global__ __launch_bounds__(256) void sel_pass1(const float* __restrict__ kt,
    float* __restrict__ cV, int* __restrict__ cI)
{
  const int hb = blockIdx.y;
  const int h = hb >> 1;
  const float sgn = (hb & 1) ? -1.f : 1.f;
  const int wv = threadIdx.x >> 6;
  const int lane = threadIdx.x & 63;
  const int base = blockIdx.x * 8192 + wv * 2048;
  const float* row = kt + (size_t)h * NTOK;

  float vals[32];
  #pragma unroll
  for (int j4 = 0; j4 < 8; j4++) {
    float4 v4 = *(const float4*)&row[base + j4 * 256 + lane * 4];
    vals[j4 * 4 + 0] = sgn * v4.x; vals[j4 * 4 + 1] = sgn * v4.y;
    vals[j4 * 4 + 2] = sgn * v4.z; vals[j4 * 4 + 3] = sgn * v4.w;
  }
  float m = NEGINF; int mj = 0;
  #pragma unroll
  for (int j = 0; j < 32; j++) if (vals[j] > m) { m = vals[j]; mj = j; }

  unsigned int used = 0u;
  const size_t slot = (size_t)hb * 4096 + (blockIdx.x * 4 + wv) * 32;
  for (int r = 0; r < 32; r++) {
    float bv = m; int bl = lane; int bj = mj;
    #pragma unroll
    for (int off = 1; off < 64; off <<= 1) {
      float ov = __shfl_xor(bv, off, 64);
      int   ol = __shfl_xor(bl, off, 64);
      int   oj = __shfl_xor(bj, off, 64);
      if (ov > bv || (ov == bv && ol < bl)) { bv = ov; bl = ol; bj = oj; }
    }
    if (lane == 0) {
      cV[slot + r] = bv;
      cI[slot + r] = base + (bj >> 2) * 256 + bl * 4 + (bj & 3);
    }
    if (lane == bl) {
      used |= (1u << bj);
      m = NEGINF; mj = 0;
      #pragma unroll
      for (int j = 0; j < 32; j++)
        if (!((used >> j) & 1u) && vals[j] > m) { m = vals[j]; mj = j; }
    }
  }
}

// ---------------- selection pass 2: 4096 candidates -> sorted top-32 + tabK/tabV -----
// grid 256 (one per head-branch), 256 threads. Per-wave extraction of top-32 over its
// 1024 candidates, then serial 4-list merge, then the exact round-1 tabV dot.
__global__ __launch_bounds__(256) void sel_pass2(const float* __restrict__ cV,
    const int* __restrict__ cI, const float* __restrict__ x, const float* __restrict__ s,
    const float* __restrict__ nw, const float* __restrict__ Wv,
    float* __restrict__ tabK, float* __restrict__ tabV)
{
  __shared__ float lv[128];
  __shared__ int   li[128];
  __shared__ float selv[32];
  __shared__ int   seli[32];
  const int t = threadIdx.x;
  const int hb = blockIdx.x;
  const int h = hb >> 1;
  const int sb = hb & 1;
  const float sgn = sb ? -1.f : 1.f;
  const int wv = t >> 6;
  const int lane = t & 63;
  const size_t cb = (size_t)hb * 4096;

  float vals[16]; int idxs[16];
  #pragma unroll
  for (int j = 0; j < 16; j++) {
    vals[j] = cV[cb + t + j * 256];
    idxs[j] = cI[cb + t + j * 256];
  }
  float m = NEGINF; int mj = 0;
  #pragma unroll
  for (int j = 0; j < 16; j++) if (vals[j] > m) { m = vals[j]; mj = j; }

  unsigned int used = 0u;
  for (int r = 0; r < 32; r++) {
    float bv = m; int bl = lane; int bj = mj;
    #pragma unroll
    for (int off = 1; off < 64; off <<= 1) {
      float ov = __shfl_xor(bv, off, 64);
      int   ol = __shfl_xor(bl, off, 64);
      int   oj = __shfl_xor(bj, off, 64);
      if (ov > bv || (ov == bv && ol < bl)) { bv = ov; bl = ol; bj = oj; }
    }
    if (lane == 0) { lv[wv * 32 + r] = bv; li[wv * 32 + r] = 0; }  // idx filled below
    if (lane == bl) {
      // winner lane records its token index for this round via LDS
      li[wv * 32 + r] = idxs[bj];
      used |= (1u << bj);
      m = NEGINF; mj = 0;
      #pragma unroll
      for (int j = 0; j < 16; j++)
        if (!((used >> j) & 1u) && vals[j] > m) { m = vals[j]; mj = j; }
    }
  }
  __syncthreads();

  if (t == 0) {   // serial merge of 4 descending lists of 32
    int p[4] = {0, 0, 0, 0};
    for (int r = 0; r < 32; r++) {
      float best = NEGINF; int bw = 0;
      #pragma unroll
      for (int w = 0; w < 4; w++) {
        if (p[w] < 32) {
          float v = lv[w * 32 + p[w]];
          if (v > best) { best = v; bw = w; }
        }
      }
      selv[r] = best;
      seli[r] = li[bw * 32 + p[bw]];
      p[bw]++;
    }
  }
  __syncthreads();

  if (t < 32) {   // EXACT round-1 epilogue
    float kval = sgn * selv[t];
    int idx = seli[t];
    tabK[(sb * 32 + t) * 128 + h] = kval * LOG2E;
    float acc = 0.f;
    const float* xr = &x[(size_t)idx * 128];
    const float* wvp = &Wv[h * 128];
    for (int k = 0; k < 128; k++) acc = fmaf(xr[k] * nw[k], wvp[k], acc);
    tabV[(sb * 32 + t) * 128 + h] = acc * s[idx];
  }
}

// ---------------- attention: in-place q[tok][h] -> softmax(q*k_sel).v_sel -------------
__global__ __launch_bounds__(256) void att_kernel(float* __restrict__ q,
    const float* __restrict__ tabK, const float* __restrict__ tabV)
{
  __shared__ float tk[8192];
  __shared__ float tv[8192];
  const int t = threadIdx.x;
  for (int i = t; i < 8192; i += 256) { tk[i] = tabK[i]; tv[i] = tabV[i]; }
  __syncthreads();
  const int h = t & 127;
  const int base = blockIdx.x * 128;   // grid 2048
  for (int it = 0; it < 64; it++) {
    const int tok = base + it * 2 + (t >> 7);
    const size_t off = (size_t)tok * 128 + h;
    const float qv = q[off];
    const int b = (qv > 0.f) ? 0 : 4096;
    const float* kk = &tk[b + h];
    const float* vv = &tv[b + h];
    float sw = 0.f, swv = 0.f;
    #pragma unroll
    for (int j = 0; j < 32; j++) {
      float e = exp2f(qv * kk[j * 128]);
      sw += e;
      swv = fmaf(e, vv[j * 128], swv);
    }
    q[off] = swv / sw;
  }
}

// ---------------- silu-mul: g = silu(g) * u (f32, in-place over g) ----------------
__global__ __launch_bounds__(256) void silu_kernel(float* __restrict__ g,
    const float* __restrict__ u, int n4)
{
  int idx = blockIdx.x * 256 + threadIdx.x;
  for (int i = idx; i < n4; i += gridDim.x * 256) {
    float4 gv = *(float4*)&g[(size_t)i * 4];
    float4 uv = *(const float4*)&u[(size_t)i * 4];
    float4 o;
    o.x = gv.x / (1.f + expf(-gv.x)) * uv.x;
    o.y = gv.y / (1.f + expf(-gv.y)) * uv.y;
    o.z = gv.z / (1.f + expf(-gv.z)) * uv.z;
    o.w = gv.w / (1.f + expf(-gv.w)) * uv.w;
    *(float4*)&g[(size_t)i * 4] = o;
  }
}

// ---------------- host orchestration ----------------
// ws layout unchanged from round 1. Candidate scratch (16.8 MB) lives in d_out,
// which is dead until the final head GEMM.

extern "C" void kernel_launch(void* const* d_in, const int* in_sizes, int n_in,
                              void* d_out, int out_size, void* d_ws, size_t ws_size,
                              hipStream_t stream)
{
  (void)in_sizes; (void)n_in; (void)out_size; (void)ws_size;
  const int*   bytes = (const int*)d_in[0];
  const float* be    = (const float*)d_in[1];
  const float* bpe   = (const float*)d_in[2];
  const float* lpe   = (const float*)d_in[3];
  const float* Wq    = (const float*)d_in[4];
  const float* Wk    = (const float*)d_in[5];
  const float* Wv    = (const float*)d_in[6];
  const float* Wo    = (const float*)d_in[7];
  const float* n1w   = (const float*)d_in[8];
  const float* n2w   = (const float*)d_in[9];
  const float* wg    = (const float*)d_in[10];
  const float* wu    = (const float*)d_in[11];
  const float* wd    = (const float*)d_in[12];
  const float* fnw   = (const float*)d_in[13];
  const float* outw  = (const float*)d_in[14];
  float* out = (float*)d_out;

  char* ws = (char*)d_ws;
  float* x    = (float*)(ws + 0);
  float* q    = (float*)(ws + 134217728);
  float* kt   = (float*)(ws + 268435456);
  float* s    = (float*)(ws + 402653184);
  float* tabK = (float*)(ws + 403701760);
  float* tabV = (float*)(ws + 403734528);
  float* gbuf = kt;
  float* ubuf = kt + 12582912;
  float* cV   = out;                       // candidate scratch in d_out
  int*   cI   = (int*)(out + 256 * 4096);  // 256 hb * 4096 * (4+4)B = 8.4 MB

  embed_kernel<<<32768, 256, 0, stream>>>(bytes, be, bpe, lpe, x);

  for (int l = 0; l < 2; l++) {
    const float* wq = Wq + l * 16384;
    const float* wk = Wk + l * 16384;
    const float* wv = Wv + l * 16384;
    const float* wo = Wo + l * 16384;
    const float* g1 = n1w + l * 128;
    const float* g2 = n2w + l * 128;
    const float* wgl = wg + l * 43648;
    const float* wul = wu + l * 43648;
    const float* wdl = wd + l * 43648;

    scale_kernel<<<1024, 256, 0, stream>>>(x, s);
    gemm_f32<M32_QK><<<dim3(4096, 2), 256, 0, stream>>>(
        x, s, g1, wq, wk, 128, 128, 128, 128, q, kt, 128);
    sel_pass1<<<dim3(32, 256), 256, 0, stream>>>(kt, cV, cI);
    sel_pass2<<<256, 256, 0, stream>>>(cV, cI, x, s, g1, wv, tabK, tabV);
    att_kernel<<<2048, 256, 0, stream>>>(q, tabK, tabV);
    gemm_f32<M32_RESID><<<dim3(4096, 1), 256, 0, stream>>>(
        q, nullptr, nullptr, wo, nullptr, 128, 128, 128, 128, x, nullptr, 128);

    scale_kernel<<<1024, 256, 0, stream>>>(x, s);
    for (int c = 0; c < 8; c++) {
      const size_t base = (size_t)c * 32768;
      gemm_f32<M32_RAW><<<dim3(512, 3), 256, 0, stream>>>(
          x + base * 128, s + base, g2, wgl, nullptr, 128, 128, 341, 128,
          gbuf, nullptr, 384);
      gemm_f32<M32_RAW><<<dim3(512, 3), 256, 0, stream>>>(
          x + base * 128, s + base, g2, wul, nullptr, 128, 128, 341, 128,
          ubuf, nullptr, 384);
      silu_kernel<<<3072, 256, 0, stream>>>(gbuf, ubuf, 3145728);
      gemm_f32<M32_RESID><<<dim3(512, 1), 256, 0, stream>>>(
          gbuf, nullptr, nullptr, wdl, nullptr, 384, 341, 128, 341,
          x + base * 128, nullptr, 128);
    }
  }

  scale_kernel<<<1024, 256, 0, stream>>>(x, s);
  gemm_f32<M32_RAW><<<dim3(4096, 2), 256, 0, stream>>>(
      x, s, fnw, outw, nullptr, 128, 128, 256, 128, out, nullptr, 256);
}

// Round 4
// 5660.497 us; speedup vs baseline: 1.7458x; 1.1104x over previous
//
#include <hip/hip_runtime.h>

// C4Transformer forward, MI355X. Round 4:
//  - pre-discrete path (layer-0 everything, both layers' QK GEMMs, selection,
//    attention inputs) BIT-IDENTICAL to round 3 (absmax margin is 8e-4; discrete
//    q-sign / top-32 decisions amplify any arithmetic change).
//  - att_kernel: 512-thread blocks (2 blocks/CU -> 50% occupancy, was 21%).
//  - post-discrete GEMMs (layer-1 Wo, layer-1 MLP, final head): split-bf16
//    3-term MFMA (hi/lo decomposition, rel err ~2e-5, adds <=1e-4 to output).

#define NTOK 262144
#define LOG2E 1.44269504088896340736f
#define NEGINF (-3.402823466e38f)

typedef unsigned short u16;
typedef short s16x8 __attribute__((ext_vector_type(8)));
typedef float f32x4 __attribute__((ext_vector_type(4)));

__device__ __forceinline__ float b2f(u16 u) {
  unsigned int x = ((unsigned int)u) << 16;
  return __builtin_bit_cast(float, x);
}
__device__ __forceinline__ u16 f2b(float f) {
  unsigned int x = __builtin_bit_cast(unsigned int, f);
  x = x + 0x7fffu + ((x >> 16) & 1u);   // RNE
  return (u16)(x >> 16);
}

// ---------------- embed ----------------
__global__ __launch_bounds__(256) void embed_kernel(const int* __restrict__ bytes,
    const float* __restrict__ be, const float* __restrict__ bpe,
    const float* __restrict__ lpe, float* __restrict__ x)
{
  int i4 = blockIdx.x * 256 + threadIdx.x;
  int n  = i4 >> 5;
  int dq = (i4 & 31) * 4;
  int b  = bytes[n];
  float4 a = *(const float4*)(be  + b * 128 + dq);
  float4 c = *(const float4*)(bpe + (n >> 8) * 128 + dq);
  float4 d = *(const float4*)(lpe + (n & 255) * 128 + dq);
  float4 o;
  o.x = (a.x + c.x) + d.x; o.y = (a.y + c.y) + d.y;
  o.z = (a.z + c.z) + d.z; o.w = (a.w + c.w) + d.w;
  *(float4*)(x + (size_t)n * 128 + dq) = o;
}

// ---------------- per-token rms scale ----------------
__global__ __launch_bounds__(256) void scale_kernel(const float* __restrict__ x,
    float* __restrict__ s)
{
  const int lane = threadIdx.x & 63;
  const int gw = blockIdx.x * 4 + (threadIdx.x >> 6);
  for (int tok = gw; tok < NTOK; tok += 4096) {
    const float2 v = *(const float2*)&x[(size_t)tok * 128 + lane * 2];
    float ss = v.x * v.x + v.y * v.y;
    #pragma unroll
    for (int off = 1; off < 64; off <<= 1) ss += __shfl_xor(ss, off, 64);
    const float m = ss * (1.f / 128.f) + 1.1920929e-07f;
    float r = rsqrtf(m);
    r = r * (1.5f - 0.5f * m * r * r);
    if (lane == 0) s[tok] = r;
  }
}

// ---------------- f32 GEMM (pre-discrete; UNCHANGED, bit-exact) ----------------
enum { M32_QK = 0, M32_RESID = 1, M32_RAW = 2 };

template<int MODE>
__global__ __launch_bounds__(256) void gemm_f32(
    const float* __restrict__ A, const float* __restrict__ rs, const float* __restrict__ cw,
    const float* __restrict__ B, const float* __restrict__ Bb,
    int K, int ldb, int Brows, int Bkcols,
    float* __restrict__ O, float* __restrict__ O2, int ldo)
{
  __shared__ float La[64][68];
  __shared__ float Lb[64][132];
  __shared__ float cwS[128];
  const int t = threadIdx.x;
  const int m0 = blockIdx.x * 64;
  const int n0 = (MODE == M32_QK) ? 0 : blockIdx.y * 128;
  const float* Bu = (MODE == M32_QK && blockIdx.y) ? Bb : B;
  for (int i = t; i < 128; i += 256) cwS[i] = cw ? cw[i] : 1.f;
  __syncthreads();

  float acc[4][8] = {};
  const int ta = (t & 15) * 4;
  const int tb = (t >> 4) * 8;

  for (int k0 = 0; k0 < K; k0 += 64) {
    for (int c = t; c < 1024; c += 256) {
      int tok = c >> 4, k4 = (c & 15) * 4;
      float4 av = *(const float4*)&A[(size_t)(m0 + tok) * K + k0 + k4];
      float rsv = rs ? rs[m0 + tok] : 1.f;
      La[k4 + 0][tok] = av.x * rsv * cwS[(k0 + k4 + 0) & 127];
      La[k4 + 1][tok] = av.y * rsv * cwS[(k0 + k4 + 1) & 127];
      La[k4 + 2][tok] = av.z * rsv * cwS[(k0 + k4 + 2) & 127];
      La[k4 + 3][tok] = av.w * rsv * cwS[(k0 + k4 + 3) & 127];
    }
    for (int c = t; c < 2048; c += 256) {
      int col = c >> 4, k4 = (c & 15) * 4;
      int gr = n0 + col;
      float4 bv = make_float4(0.f, 0.f, 0.f, 0.f);
      if (gr < Brows) {
        int kb = k0 + k4;
        if (((ldb & 3) == 0) && kb + 3 < Bkcols) {
          bv = *(const float4*)&Bu[(size_t)gr * ldb + kb];
        } else {
          float* bp = (float*)&bv;
          #pragma unroll
          for (int j = 0; j < 4; j++)
            if (kb + j < Bkcols) bp[j] = Bu[(size_t)gr * ldb + kb + j];
        }
      }
      Lb[k4 + 0][col] = bv.x; Lb[k4 + 1][col] = bv.y;
      Lb[k4 + 2][col] = bv.z; Lb[k4 + 3][col] = bv.w;
    }
    __syncthreads();
    for (int kq = 0; kq < 64; kq += 4) {
      float aa[4][4], bb[4][8];
      #pragma unroll
      for (int kk = 0; kk < 4; kk++) {
        *(float4*)&aa[kk][0] = *(const float4*)&La[kq + kk][ta];
        *(float4*)&bb[kk][0] = *(const float4*)&Lb[kq + kk][tb];
        *(float4*)&bb[kk][4] = *(const float4*)&Lb[kq + kk][tb + 4];
      }
      #pragma unroll
      for (int i = 0; i < 4; i++)
        #pragma unroll
        for (int j = 0; j < 8; j++) {
          float tt = aa[0][i] * bb[0][j];
          tt = fmaf(aa[1][i], bb[1][j], tt);
          tt = fmaf(aa[2][i], bb[2][j], tt);
          tt = fmaf(aa[3][i], bb[3][j], tt);
          acc[i][j] += tt;
        }
    }
    __syncthreads();
  }

  if (MODE == M32_QK) {
    if (blockIdx.y == 0) {
      #pragma unroll
      for (int i = 0; i < 4; i++)
        #pragma unroll
        for (int j = 0; j < 8; j++)
          O[(size_t)(m0 + ta + i) * 128 + tb + j] = acc[i][j];
    } else {
      #pragma unroll
      for (int i = 0; i < 4; i++)
        #pragma unroll
        for (int j = 0; j < 8; j++)
          O2[(size_t)(tb + j) * NTOK + (m0 + ta + i)] = acc[i][j];
    }
  } else if (MODE == M32_RESID) {
    #pragma unroll
    for (int i = 0; i < 4; i++)
      #pragma unroll
      for (int j = 0; j < 8; j++) {
        size_t ix = (size_t)(m0 + ta + i) * ldo + n0 + tb + j;
        O[ix] += acc[i][j];
      }
  } else {
    #pragma unroll
    for (int i = 0; i < 4; i++)
      #pragma unroll
      for (int j = 0; j < 8; j++)
        O[(size_t)(m0 + ta + i) * ldo + n0 + tb + j] = acc[i][j];
  }
}

// ---------------- weight split prep: w -> (hi, lo) bf16 arenas, zero-padded --------
// u16 arena layout: [0,49152) gate l1 [384][128]; [49152,98304) up l1;
// [98304,147456) down l1 [128][384]; [147456,163840) wo l1 [128][128];
// [163840,196608) head [256][128].
__global__ __launch_bounds__(256) void prep_split(const float* __restrict__ wg,
    const float* __restrict__ wu, const float* __restrict__ wd,
    const float* __restrict__ wo, const float* __restrict__ ow,
    u16* __restrict__ whi, u16* __restrict__ wlo)
{
  const int i = blockIdx.x * 256 + threadIdx.x;   // grid 768
  float val = 0.f;
  if (i < 49152) {
    int r = i >> 7, k = i & 127;
    if (r < 341) val = wg[43648 + r * 128 + k];
  } else if (i < 98304) {
    int j = i - 49152, r = j >> 7, k = j & 127;
    if (r < 341) val = wu[43648 + r * 128 + k];
  } else if (i < 147456) {
    int j = i - 98304, r = j / 384, c = j % 384;
    if (c < 341) val = wd[43648 + r * 341 + c];
  } else if (i < 163840) {
    val = wo[16384 + (i - 147456)];
  } else {
    val = ow[i - 163840];
  }
  u16 h = f2b(val);
  whi[i] = h;
  wlo[i] = f2b(val - b2f(h));
}

// ---------------- split-bf16 3-term MFMA GEMM (post-discrete only) ----------------
// C = (A .* rs .* cw)[M][K] * B[N][K]^T, B pre-split (hi,lo) u16, zero-padded.
// 64x64 tile, 4 waves (32x32 quadrants), mfma_f32_16x16x32_bf16.
// acc += Ahi*Bhi + Ahi*Blo + Alo*Bhi  (rel err ~2^-16).
enum { MB_RAW = 0, MB_RESID = 1 };

template<int MODE>
__global__ __launch_bounds__(256) void gemm_bf3(
    const float* __restrict__ A, const float* __restrict__ rs, const float* __restrict__ cw,
    int K, const u16* __restrict__ Bhi, const u16* __restrict__ Blo, int ldb,
    float* __restrict__ O, int ldo)
{
  __shared__ u16 sAhi[64 * 136];
  __shared__ u16 sAlo[64 * 136];
  __shared__ u16 sBhi[64 * 136];
  __shared__ u16 sBlo[64 * 136];
  __shared__ float cwS[128];
  const int t = threadIdx.x;
  const int lane = t & 63;
  const int w = t >> 6;
  const int wr = w >> 1, wc = w & 1;
  const int m0 = blockIdx.x * 64;
  const int n0 = blockIdx.y * 64;
  const int l15 = lane & 15;
  const int lg  = lane >> 4;
  for (int i = t; i < 128; i += 256) cwS[i] = cw ? cw[i] : 1.f;
  __syncthreads();

  f32x4 acc[2][2] = {};

  for (int k0 = 0; k0 < K; k0 += 128) {
    for (int c = t; c < 2048; c += 256) {          // A: 64 rows x 128 k (f32 -> hi/lo)
      int row = c >> 5, k4 = (c & 31) * 4;
      float4 av = *(const float4*)&A[(size_t)(m0 + row) * K + k0 + k4];
      float rsv = rs ? rs[m0 + row] : 1.f;
      float vv[4] = { av.x, av.y, av.z, av.w };
      ushort4 hv, lv;
      u16* hp = (u16*)&hv; u16* lp = (u16*)&lv;
      #pragma unroll
      for (int j = 0; j < 4; j++) {
        float a = vv[j] * rsv * cwS[(k4 + j) & 127];   // cw only used when K==128
        u16 h = f2b(a);
        hp[j] = h;
        lp[j] = f2b(a - b2f(h));
      }
      *(ushort4*)&sAhi[row * 136 + k4] = hv;
      *(ushort4*)&sAlo[row * 136 + k4] = lv;
    }
    for (int c = t; c < 1024; c += 256) {          // B: 64 cols x 128 k, pre-split u16
      int row = c >> 4, k8 = (c & 15) * 8;
      *(uint4*)&sBhi[row * 136 + k8] = *(const uint4*)&Bhi[(size_t)(n0 + row) * ldb + k0 + k8];
      *(uint4*)&sBlo[row * 136 + k8] = *(const uint4*)&Blo[(size_t)(n0 + row) * ldb + k0 + k8];
    }
    __syncthreads();
    #pragma unroll
    for (int ks = 0; ks < 4; ks++) {
      s16x8 ah[2], al[2], bh[2], bl[2];
      #pragma unroll
      for (int mr = 0; mr < 2; mr++) {
        int off = (wr * 32 + mr * 16 + l15) * 136 + ks * 32 + lg * 8;
        ah[mr] = *(const s16x8*)&sAhi[off];
        al[mr] = *(const s16x8*)&sAlo[off];
      }
      #pragma unroll
      for (int nr = 0; nr < 2; nr++) {
        int off = (wc * 32 + nr * 16 + l15) * 136 + ks * 32 + lg * 8;
        bh[nr] = *(const s16x8*)&sBhi[off];
        bl[nr] = *(const s16x8*)&sBlo[off];
      }
      #pragma unroll
      for (int mr = 0; mr < 2; mr++)
        #pragma unroll
        for (int nr = 0; nr < 2; nr++) {
          acc[mr][nr] = __builtin_amdgcn_mfma_f32_16x16x32_bf16(ah[mr], bh[nr], acc[mr][nr], 0, 0, 0);
          acc[mr][nr] = __builtin_amdgcn_mfma_f32_16x16x32_bf16(ah[mr], bl[nr], acc[mr][nr], 0, 0, 0);
          acc[mr][nr] = __builtin_amdgcn_mfma_f32_16x16x32_bf16(al[mr], bh[nr], acc[mr][nr], 0, 0, 0);
        }
    }
    __syncthreads();
  }

  // D mapping: row = (lane>>4)*4 + reg, col = lane&15
  #pragma unroll
  for (int mr = 0; mr < 2; mr++)
    #pragma unroll
    for (int nr = 0; nr < 2; nr++)
      #pragma unroll
      for (int r = 0; r < 4; r++) {
        int row = m0 + wr * 32 + mr * 16 + lg * 4 + r;
        int col = n0 + wc * 32 + nr * 16 + l15;
        size_t ix = (size_t)row * ldo + col;
        if (MODE == MB_RESID) O[ix] += acc[mr][nr][r];
        else                  O[ix]  = acc[mr][nr][r];
      }
}

// ---------------- selection pass 1 (unchanged) ----------------
__global__ __launch_bounds__(256) void sel_pass1(const float* __restrict__ kt,
    float* __restrict__ cV, int* __restrict__ cI)
{
  const int hb = blockIdx.y;
  const int h = hb >> 1;
  const float sgn = (hb & 1) ? -1.f : 1.f;
  const int wv = threadIdx.x >> 6;
  const int lane = threadIdx.x & 63;
  const int base = blockIdx.x * 8192 + wv * 2048;
  const float* row = kt + (size_t)h * NTOK;

  float vals[32];
  #pragma unroll
  for (int j4 = 0; j4 < 8; j4++) {
    float4 v4 = *(const float4*)&row[base + j4 * 256 + lane * 4];
    vals[j4 * 4 + 0] = sgn * v4.x; vals[j4 * 4 + 1] = sgn * v4.y;
    vals[j4 * 4 + 2] = sgn * v4.z; vals[j4 * 4 + 3] = sgn * v4.w;
  }
  float m = NEGINF; int mj = 0;
  #pragma unroll
  for (int j = 0; j < 32; j++) if (vals[j] > m) { m = vals[j]; mj = j; }

  unsigned int used = 0u;
  const size_t slot = (size_t)hb * 4096 + (blockIdx.x * 4 + wv) * 32;
  for (int r = 0; r < 32; r++) {
    float bv = m; int bl = lane; int bj = mj;
    #pragma unroll
    for (int off = 1; off < 64; off <<= 1) {
      float ov = __shfl_xor(bv, off, 64);
      int   ol = __shfl_xor(bl, off, 64);
      int   oj = __shfl_xor(bj, off, 64);
      if (ov > bv || (ov == bv && ol < bl)) { bv = ov; bl = ol; bj = oj; }
    }
    if (lane == 0) {
      cV[slot + r] = bv;
      cI[slot + r] = base + (bj >> 2) * 256 + bl * 4 + (bj & 3);
    }
    if (lane == bl) {
      used |= (1u << bj);
      m = NEGINF; mj = 0;
      #pragma unroll
      for (int j = 0; j < 32; j++)
        if (!((used >> j) & 1u) && vals[j] > m) { m = vals[j]; mj = j; }
    }
  }
}

// ---------------- selection pass 2 (unchanged) ----------------
__global__ __launch_bounds__(256) void sel_pass2(const float* __restrict__ cV,
    const int* __restrict__ cI, const float* __restrict__ x, const float* __restrict__ s,
    const float* __restrict__ nw, const float* __restrict__ Wv,
    float* __restrict__ tabK, float* __restrict__ tabV)
{
  __shared__ float lv[128];
  __shared__ int   li[128];
  __shared__ float selv[32];
  __shared__ int   seli[32];
  const int t = threadIdx.x;
  const int hb = blockIdx.x;
  const int h = hb >> 1;
  const int sb = hb & 1;
  const float sgn = sb ? -1.f : 1.f;
  const int wv = t >> 6;
  const int lane = t & 63;
  const size_t cb = (size_t)hb * 4096;

  float vals[16]; int idxs[16];
  #pragma unroll
  for (int j = 0; j < 16; j++) {
    vals[j] = cV[cb + t + j * 256];
    idxs[j] = cI[cb + t + j * 256];
  }
  float m = NEGINF; int mj = 0;
  #pragma unroll
  for (int j = 0; j < 16; j++) if (vals[j] > m) { m = vals[j]; mj = j; }

  unsigned int used = 0u;
  for (int r = 0; r < 32; r++) {
    float bv = m; int bl = lane; int bj = mj;
    #pragma unroll
    for (int off = 1; off < 64; off <<= 1) {
      float ov = __shfl_xor(bv, off, 64);
      int   ol = __shfl_xor(bl, off, 64);
      int   oj = __shfl_xor(bj, off, 64);
      if (ov > bv || (ov == bv && ol < bl)) { bv = ov; bl = ol; bj = oj; }
    }
    if (lane == 0) { lv[wv * 32 + r] = bv; li[wv * 32 + r] = 0; }
    if (lane == bl) {
      li[wv * 32 + r] = idxs[bj];
      used |= (1u << bj);
      m = NEGINF; mj = 0;
      #pragma unroll
      for (int j = 0; j < 16; j++)
        if (!((used >> j) & 1u) && vals[j] > m) { m = vals[j]; mj = j; }
    }
  }
  __syncthreads();

  if (t == 0) {
    int p[4] = {0, 0, 0, 0};
    for (int r = 0; r < 32; r++) {
      float best = NEGINF; int bw = 0;
      #pragma unroll
      for (int w = 0; w < 4; w++) {
        if (p[w] < 32) {
          float v = lv[w * 32 + p[w]];
          if (v > best) { best = v; bw = w; }
        }
      }
      selv[r] = best;
      seli[r] = li[bw * 32 + p[bw]];
      p[bw]++;
    }
  }
  __syncthreads();

  if (t < 32) {
    float kval = sgn * selv[t];
    int idx = seli[t];
    tabK[(sb * 32 + t) * 128 + h] = kval * LOG2E;
    float acc = 0.f;
    const float* xr = &x[(size_t)idx * 128];
    const float* wvp = &Wv[h * 128];
    for (int k = 0; k < 128; k++) acc = fmaf(xr[k] * nw[k], wvp[k], acc);
    tabV[(sb * 32 + t) * 128 + h] = acc * s[idx];
  }
}

// ---------------- attention: 512 threads (2 blocks/CU = 50% occupancy) --------------
// Per-(tok,h) arithmetic identical to round 3 (bit-exact).
__global__ __launch_bounds__(512) void att_kernel(float* __restrict__ q,
    const float* __restrict__ tabK, const float* __restrict__ tabV)
{
  __shared__ float tk[8192];
  __shared__ float tv[8192];
  const int t = threadIdx.x;
  for (int i = t; i < 8192; i += 512) { tk[i] = tabK[i]; tv[i] = tabV[i]; }
  __syncthreads();
  const int h = t & 127;
  const int base = blockIdx.x * 256;   // grid 1024 x 256 tokens
  for (int it = 0; it < 64; it++) {
    const int tok = base + it * 4 + (t >> 7);
    const size_t off = (size_t)tok * 128 + h;
    const float qv = q[off];
    const int b = (qv > 0.f) ? 0 : 4096;
    const float* kk = &tk[b + h];
    const float* vv = &tv[b + h];
    float sw = 0.f, swv = 0.f;
    #pragma unroll
    for (int j = 0; j < 32; j++) {
      float e = exp2f(qv * kk[j * 128]);
      sw += e;
      swv = fmaf(e, vv[j * 128], swv);
    }
    q[off] = swv / sw;
  }
}

// ---------------- silu-mul (unchanged) ----------------
__global__ __launch_bounds__(256) void silu_kernel(float* __restrict__ g,
    const float* __restrict__ u, int n4)
{
  int idx = blockIdx.x * 256 + threadIdx.x;
  for (int i = idx; i < n4; i += gridDim.x * 256) {
    float4 gv = *(float4*)&g[(size_t)i * 4];
    float4 uv = *(const float4*)&u[(size_t)i * 4];
    float4 o;
    o.x = gv.x / (1.f + expf(-gv.x)) * uv.x;
    o.y = gv.y / (1.f + expf(-gv.y)) * uv.y;
    o.z = gv.z / (1.f + expf(-gv.z)) * uv.z;
    o.w = gv.w / (1.f + expf(-gv.w)) * uv.w;
    *(float4*)&g[(size_t)i * 4] = o;
  }
}

// ---------------- host orchestration ----------------
// ws layout (bytes):
//   [0, 134217728)           x residual (f32)
//   [134217728, 268435456)   q (f32)
//   [268435456, 402653184)   kt / MLP g,u scratch
//   [402653184, 403701760)   s per-token scales
//   [403701760, 403734528)   tabK ; [403734528, 403767296) tabV
//   [403767296, 404160512)   whi arena (u16[196608])
//   [404160512, 404553728)   wlo arena
// sel candidate scratch (16.8 MB) lives in d_out (dead until final head).

extern "C" void kernel_launch(void* const* d_in, const int* in_sizes, int n_in,
                              void* d_out, int out_size, void* d_ws, size_t ws_size,
                              hipStream_t stream)
{
  (void)in_sizes; (void)n_in; (void)out_size; (void)ws_size;
  const int*   bytes = (const int*)d_in[0];
  const float* be    = (const float*)d_in[1];
  const float* bpe   = (const float*)d_in[2];
  const float* lpe   = (const float*)d_in[3];
  const float* Wq    = (const float*)d_in[4];
  const float* Wk    = (const float*)d_in[5];
  const float* Wv    = (const float*)d_in[6];
  const float* Wo    = (const float*)d_in[7];
  const float* n1w   = (const float*)d_in[8];
  const float* n2w   = (const float*)d_in[9];
  const float* wg    = (const float*)d_in[10];
  const float* wu    = (const float*)d_in[11];
  const float* wd    = (const float*)d_in[12];
  const float* fnw   = (const float*)d_in[13];
  const float* outw  = (const float*)d_in[14];
  float* out = (float*)d_out;

  char* ws = (char*)d_ws;
  float* x    = (float*)(ws + 0);
  float* q    = (float*)(ws + 134217728);
  float* kt   = (float*)(ws + 268435456);
  float* s    = (float*)(ws + 402653184);
  float* tabK = (float*)(ws + 403701760);
  float* tabV = (float*)(ws + 403734528);
  u16*   whi  = (u16*)(ws + 403767296);
  u16*   wlo  = (u16*)(ws + 404160512);
  float* gbuf = kt;
  float* ubuf = kt + 12582912;
  float* cV   = out;
  int*   cI   = (int*)(out + 256 * 4096);

  // arena offsets (u16 elems)
  const size_t AG = 0, AU = 49152, AD = 98304, AW = 147456, AH = 163840;

  prep_split<<<768, 256, 0, stream>>>(wg, wu, wd, Wo, outw, whi, wlo);
  embed_kernel<<<32768, 256, 0, stream>>>(bytes, be, bpe, lpe, x);

  for (int l = 0; l < 2; l++) {
    const float* wq = Wq + l * 16384;
    const float* wk = Wk + l * 16384;
    const float* wv = Wv + l * 16384;
    const float* wo = Wo + l * 16384;
    const float* g1 = n1w + l * 128;
    const float* g2 = n2w + l * 128;
    const float* wgl = wg + l * 43648;
    const float* wul = wu + l * 43648;
    const float* wdl = wd + l * 43648;

    scale_kernel<<<1024, 256, 0, stream>>>(x, s);
    gemm_f32<M32_QK><<<dim3(4096, 2), 256, 0, stream>>>(
        x, s, g1, wq, wk, 128, 128, 128, 128, q, kt, 128);
    sel_pass1<<<dim3(32, 256), 256, 0, stream>>>(kt, cV, cI);
    sel_pass2<<<256, 256, 0, stream>>>(cV, cI, x, s, g1, wv, tabK, tabV);
    att_kernel<<<1024, 512, 0, stream>>>(q, tabK, tabV);

    if (l == 0) {
      // ---- pre-discrete: exact f32 path (bit-identical to round 3) ----
      gemm_f32<M32_RESID><<<dim3(4096, 1), 256, 0, stream>>>(
          q, nullptr, nullptr, wo, nullptr, 128, 128, 128, 128, x, nullptr, 128);
      scale_kernel<<<1024, 256, 0, stream>>>(x, s);
      for (int c = 0; c < 8; c++) {
        const size_t base = (size_t)c * 32768;
        gemm_f32<M32_RAW><<<dim3(512, 3), 256, 0, stream>>>(
            x + base * 128, s + base, g2, wgl, nullptr, 128, 128, 341, 128,
            gbuf, nullptr, 384);
        gemm_f32<M32_RAW><<<dim3(512, 3), 256, 0, stream>>>(
            x + base * 128, s + base, g2, wul, nullptr, 128, 128, 341, 128,
            ubuf, nullptr, 384);
        silu_kernel<<<3072, 256, 0, stream>>>(gbuf, ubuf, 3145728);
        gemm_f32<M32_RESID><<<dim3(512, 1), 256, 0, stream>>>(
            gbuf, nullptr, nullptr, wdl, nullptr, 384, 341, 128, 341,
            x + base * 128, nullptr, 128);
      }
    } else {
      // ---- post-discrete: split-bf16 3-term MFMA ----
      gemm_bf3<MB_RESID><<<dim3(4096, 2), 256, 0, stream>>>(
          q, nullptr, nullptr, 128, whi + AW, wlo + AW, 128, x, 128);
      scale_kernel<<<1024, 256, 0, stream>>>(x, s);
      for (int c = 0; c < 8; c++) {
        const size_t base = (size_t)c * 32768;
        gemm_bf3<MB_RAW><<<dim3(512, 6), 256, 0, stream>>>(
            x + base * 128, s + base, g2, 128, whi + AG, wlo + AG, 128, gbuf, 384);
        gemm_bf3<MB_RAW><<<dim3(512, 6), 256, 0, stream>>>(
            x + base * 128, s + base, g2, 128, whi + AU, wlo + AU, 128, ubuf, 384);
        silu_kernel<<<3072, 256, 0, stream>>>(gbuf, ubuf, 3145728);
        gemm_bf3<MB_RESID><<<dim3(512, 2), 256, 0, stream>>>(
            gbuf, nullptr, nullptr, 384, whi + AD, wlo + AD, 384, x + base * 128, 128);
      }
    }
  }

  scale_kernel<<<1024, 256, 0, stream>>>(x, s);
  gemm_bf3<MB_RAW><<<dim3(4096, 4), 256, 0, stream>>>(
      x, s, fnw, 128, whi + AH, wlo + AH, 128, out, 256);
}

// Round 5
// 5030.755 us; speedup vs baseline: 1.9643x; 1.1252x over previous
//
#include <hip/hip_runtime.h>

// C4Transformer forward, MI355X. Round 5:
//  - pre-discrete datapath VALUES bit-identical to round 4 (absmax margin 8e-4;
//    discrete q-sign / top-32 decisions amplify any arithmetic change).
//  - f32 GEMM: XOR-swizzled LDS staging (kills 16-way transpose-write conflicts;
//    pure layout permutation, bit-exact).
//  - gate/up/silu fused into one kernel per layer (identical per-output chains).
//  - att: float2 k/v table, 2-token ILP; layer-1 (post-discrete) uses raw
//    v_exp_f32 + rcp, layer-0 keeps exp2f/div (bit-exact).

#define NTOK 262144
#define LOG2E 1.44269504088896340736f
#define NEGINF (-3.402823466e38f)

typedef unsigned short u16;
typedef short s16x8 __attribute__((ext_vector_type(8)));
typedef float f32x4 __attribute__((ext_vector_type(4)));

__device__ __forceinline__ float b2f(u16 u) {
  unsigned int x = ((unsigned int)u) << 16;
  return __builtin_bit_cast(float, x);
}
__device__ __forceinline__ u16 f2b(float f) {
  unsigned int x = __builtin_bit_cast(unsigned int, f);
  x = x + 0x7fffu + ((x >> 16) & 1u);   // RNE
  return (u16)(x >> 16);
}

// ---------------- embed ----------------
__global__ __launch_bounds__(256) void embed_kernel(const int* __restrict__ bytes,
    const float* __restrict__ be, const float* __restrict__ bpe,
    const float* __restrict__ lpe, float* __restrict__ x)
{
  int i4 = blockIdx.x * 256 + threadIdx.x;
  int n  = i4 >> 5;
  int dq = (i4 & 31) * 4;
  int b  = bytes[n];
  float4 a = *(const float4*)(be  + b * 128 + dq);
  float4 c = *(const float4*)(bpe + (n >> 8) * 128 + dq);
  float4 d = *(const float4*)(lpe + (n & 255) * 128 + dq);
  float4 o;
  o.x = (a.x + c.x) + d.x; o.y = (a.y + c.y) + d.y;
  o.z = (a.z + c.z) + d.z; o.w = (a.w + c.w) + d.w;
  *(float4*)(x + (size_t)n * 128 + dq) = o;
}

// ---------------- per-token rms scale ----------------
__global__ __launch_bounds__(256) void scale_kernel(const float* __restrict__ x,
    float* __restrict__ s)
{
  const int lane = threadIdx.x & 63;
  const int gw = blockIdx.x * 4 + (threadIdx.x >> 6);
  for (int tok = gw; tok < NTOK; tok += 4096) {
    const float2 v = *(const float2*)&x[(size_t)tok * 128 + lane * 2];
    float ss = v.x * v.x + v.y * v.y;
    #pragma unroll
    for (int off = 1; off < 64; off <<= 1) ss += __shfl_xor(ss, off, 64);
    const float m = ss * (1.f / 128.f) + 1.1920929e-07f;
    float r = rsqrtf(m);
    r = r * (1.5f - 0.5f * m * r * r);
    if (lane == 0) s[tok] = r;
  }
}

// ---------------- f32 GEMM (pre-discrete; bit-exact values, swizzled LDS) -----------
enum { M32_QK = 0, M32_RESID = 1, M32_RAW = 2 };

template<int MODE>
__global__ __launch_bounds__(256) void gemm_f32(
    const float* __restrict__ A, const float* __restrict__ rs, const float* __restrict__ cw,
    const float* __restrict__ B, const float* __restrict__ Bb,
    int K, int ldb, int Brows, int Bkcols,
    float* __restrict__ O, float* __restrict__ O2, int ldo)
{
  __shared__ float La[64][68];
  __shared__ float Lb[64][132];
  __shared__ float cwS[128];
  const int t = threadIdx.x;
  const int m0 = blockIdx.x * 64;
  const int n0 = (MODE == M32_QK) ? 0 : blockIdx.y * 128;
  const float* Bu = (MODE == M32_QK && blockIdx.y) ? Bb : B;
  for (int i = t; i < 128; i += 256) cwS[i] = cw ? cw[i] : 1.f;
  __syncthreads();

  float acc[4][8] = {};
  const int ta = (t & 15) * 4;
  const int tb = (t >> 4) * 8;

  for (int k0 = 0; k0 < K; k0 += 64) {
    for (int c = t; c < 1024; c += 256) {
      int tok = c >> 4, k4 = (c & 15) * 4;
      const int xsw = (c & 7) << 2;           // = 4*((k4>>2)&7)
      float4 av = *(const float4*)&A[(size_t)(m0 + tok) * K + k0 + k4];
      float rsv = rs ? rs[m0 + tok] : 1.f;
      const int tokS = tok ^ xsw;
      La[k4 + 0][tokS] = av.x * rsv * cwS[(k0 + k4 + 0) & 127];
      La[k4 + 1][tokS] = av.y * rsv * cwS[(k0 + k4 + 1) & 127];
      La[k4 + 2][tokS] = av.z * rsv * cwS[(k0 + k4 + 2) & 127];
      La[k4 + 3][tokS] = av.w * rsv * cwS[(k0 + k4 + 3) & 127];
    }
    for (int c = t; c < 2048; c += 256) {
      int col = c >> 4, k4 = (c & 15) * 4;
      const int xsw = (c & 7) << 2;
      int gr = n0 + col;
      float4 bv = make_float4(0.f, 0.f, 0.f, 0.f);
      if (gr < Brows) {
        int kb = k0 + k4;
        if (((ldb & 3) == 0) && kb + 3 < Bkcols) {
          bv = *(const float4*)&Bu[(size_t)gr * ldb + kb];
        } else {
          float* bp = (float*)&bv;
          #pragma unroll
          for (int j = 0; j < 4; j++)
            if (kb + j < Bkcols) bp[j] = Bu[(size_t)gr * ldb + kb + j];
        }
      }
      const int colS = col ^ xsw;
      Lb[k4 + 0][colS] = bv.x; Lb[k4 + 1][colS] = bv.y;
      Lb[k4 + 2][colS] = bv.z; Lb[k4 + 3][colS] = bv.w;
    }
    __syncthreads();
    for (int kq = 0; kq < 64; kq += 4) {
      const int xsw = ((kq >> 2) & 7) << 2;
      float aa[4][4], bb[4][8];
      #pragma unroll
      for (int kk = 0; kk < 4; kk++) {
        *(float4*)&aa[kk][0] = *(const float4*)&La[kq + kk][ta ^ xsw];
        *(float4*)&bb[kk][0] = *(const float4*)&Lb[kq + kk][tb ^ xsw];
        *(float4*)&bb[kk][4] = *(const float4*)&Lb[kq + kk][(tb + 4) ^ xsw];
      }
      #pragma unroll
      for (int i = 0; i < 4; i++)
        #pragma unroll
        for (int j = 0; j < 8; j++) {
          float tt = aa[0][i] * bb[0][j];
          tt = fmaf(aa[1][i], bb[1][j], tt);
          tt = fmaf(aa[2][i], bb[2][j], tt);
          tt = fmaf(aa[3][i], bb[3][j], tt);
          acc[i][j] += tt;
        }
    }
    __syncthreads();
  }

  if (MODE == M32_QK) {
    if (blockIdx.y == 0) {
      #pragma unroll
      for (int i = 0; i < 4; i++)
        #pragma unroll
        for (int j = 0; j < 8; j++)
          O[(size_t)(m0 + ta + i) * 128 + tb + j] = acc[i][j];
    } else {
      #pragma unroll
      for (int i = 0; i < 4; i++)
        #pragma unroll
        for (int j = 0; j < 8; j++)
          O2[(size_t)(tb + j) * NTOK + (m0 + ta + i)] = acc[i][j];
    }
  } else if (MODE == M32_RESID) {
    #pragma unroll
    for (int i = 0; i < 4; i++)
      #pragma unroll
      for (int j = 0; j < 8; j++) {
        size_t ix = (size_t)(m0 + ta + i) * ldo + n0 + tb + j;
        O[ix] += acc[i][j];
      }
  } else {
    #pragma unroll
    for (int i = 0; i < 4; i++)
      #pragma unroll
      for (int j = 0; j < 8; j++)
        O[(size_t)(m0 + ta + i) * ldo + n0 + tb + j] = acc[i][j];
  }
}

// ---------------- fused f32 gate+up+silu (layer 0; bit-exact chains) ----------------
// tile 64 tok x 64 col (grid y=6 covers 384), writes hh = silu(g)*u directly.
__global__ __launch_bounds__(256) void gemm_f32_gu(
    const float* __restrict__ A, const float* __restrict__ rs, const float* __restrict__ cw,
    const float* __restrict__ BG, const float* __restrict__ BU,
    float* __restrict__ hh)
{
  __shared__ float La[64][68];
  __shared__ float LbG[64][68];
  __shared__ float LbU[64][68];
  __shared__ float cwS[128];
  const int t = threadIdx.x;
  const int m0 = blockIdx.x * 64;
  const int n0 = blockIdx.y * 64;
  for (int i = t; i < 128; i += 256) cwS[i] = cw[i];
  __syncthreads();

  float accG[4][4] = {}, accU[4][4] = {};
  const int ta = (t & 15) * 4;
  const int tb = (t >> 4) * 4;

  for (int k0 = 0; k0 < 128; k0 += 64) {
    for (int c = t; c < 1024; c += 256) {
      int tok = c >> 4, k4 = (c & 15) * 4;
      const int xsw = (c & 7) << 2;
      float4 av = *(const float4*)&A[(size_t)(m0 + tok) * 128 + k0 + k4];
      float rsv = rs[m0 + tok];
      const int tokS = tok ^ xsw;
      La[k4 + 0][tokS] = av.x * rsv * cwS[k0 + k4 + 0];
      La[k4 + 1][tokS] = av.y * rsv * cwS[k0 + k4 + 1];
      La[k4 + 2][tokS] = av.z * rsv * cwS[k0 + k4 + 2];
      La[k4 + 3][tokS] = av.w * rsv * cwS[k0 + k4 + 3];
    }
    for (int c = t; c < 2048; c += 256) {
      int which = c >> 10, cc = c & 1023;
      int col = cc >> 4, k4 = (cc & 15) * 4;
      const int xsw = (cc & 7) << 2;
      int gr = n0 + col;
      float4 bv = make_float4(0.f, 0.f, 0.f, 0.f);
      if (gr < 341)
        bv = *(const float4*)&(which ? BU : BG)[(size_t)gr * 128 + k0 + k4];
      float (*Lp)[68] = which ? LbU : LbG;
      const int colS = col ^ xsw;
      Lp[k4 + 0][colS] = bv.x; Lp[k4 + 1][colS] = bv.y;
      Lp[k4 + 2][colS] = bv.z; Lp[k4 + 3][colS] = bv.w;
    }
    __syncthreads();
    for (int kq = 0; kq < 64; kq += 4) {
      const int xsw = ((kq >> 2) & 7) << 2;
      float aa[4][4], bg[4][4], bu[4][4];
      #pragma unroll
      for (int kk = 0; kk < 4; kk++) {
        *(float4*)&aa[kk][0] = *(const float4*)&La[kq + kk][ta ^ xsw];
        *(float4*)&bg[kk][0] = *(const float4*)&LbG[kq + kk][tb ^ xsw];
        *(float4*)&bu[kk][0] = *(const float4*)&LbU[kq + kk][tb ^ xsw];
      }
      #pragma unroll
      for (int i = 0; i < 4; i++)
        #pragma unroll
        for (int j = 0; j < 4; j++) {
          float tg = aa[0][i] * bg[0][j];
          tg = fmaf(aa[1][i], bg[1][j], tg);
          tg = fmaf(aa[2][i], bg[2][j], tg);
          tg = fmaf(aa[3][i], bg[3][j], tg);
          accG[i][j] += tg;
          float tu = aa[0][i] * bu[0][j];
          tu = fmaf(aa[1][i], bu[1][j], tu);
          tu = fmaf(aa[2][i], bu[2][j], tu);
          tu = fmaf(aa[3][i], bu[3][j], tu);
          accU[i][j] += tu;
        }
    }
    __syncthreads();
  }

  #pragma unroll
  for (int i = 0; i < 4; i++)
    #pragma unroll
    for (int j = 0; j < 4; j++) {
      float g = accG[i][j], u = accU[i][j];
      hh[(size_t)(m0 + ta + i) * 384 + n0 + tb + j] = g / (1.f + expf(-g)) * u;
    }
}

// ---------------- weight split prep (unchanged arenas) ----------------
__global__ __launch_bounds__(256) void prep_split(const float* __restrict__ wg,
    const float* __restrict__ wu, const float* __restrict__ wd,
    const float* __restrict__ wo, const float* __restrict__ ow,
    u16* __restrict__ whi, u16* __restrict__ wlo)
{
  const int i = blockIdx.x * 256 + threadIdx.x;   // grid 768
  float val = 0.f;
  if (i < 49152) {
    int r = i >> 7, k = i & 127;
    if (r < 341) val = wg[43648 + r * 128 + k];
  } else if (i < 98304) {
    int j = i - 49152, r = j >> 7, k = j & 127;
    if (r < 341) val = wu[43648 + r * 128 + k];
  } else if (i < 147456) {
    int j = i - 98304, r = j / 384, c = j % 384;
    if (c < 341) val = wd[43648 + r * 341 + c];
  } else if (i < 163840) {
    val = wo[16384 + (i - 147456)];
  } else {
    val = ow[i - 163840];
  }
  u16 h = f2b(val);
  whi[i] = h;
  wlo[i] = f2b(val - b2f(h));
}

// ---------------- split-bf16 3-term MFMA GEMM (post-discrete) ----------------
enum { MB_RAW = 0, MB_RESID = 1 };

template<int MODE>
__global__ __launch_bounds__(256) void gemm_bf3(
    const float* __restrict__ A, const float* __restrict__ rs, const float* __restrict__ cw,
    int K, const u16* __restrict__ Bhi, const u16* __restrict__ Blo, int ldb,
    float* __restrict__ O, int ldo)
{
  __shared__ u16 sAhi[64 * 136];
  __shared__ u16 sAlo[64 * 136];
  __shared__ u16 sBhi[64 * 136];
  __shared__ u16 sBlo[64 * 136];
  __shared__ float cwS[128];
  const int t = threadIdx.x;
  const int lane = t & 63;
  const int w = t >> 6;
  const int wr = w >> 1, wc = w & 1;
  const int m0 = blockIdx.x * 64;
  const int n0 = blockIdx.y * 64;
  const int l15 = lane & 15;
  const int lg  = lane >> 4;
  for (int i = t; i < 128; i += 256) cwS[i] = cw ? cw[i] : 1.f;
  __syncthreads();

  f32x4 acc[2][2] = {};

  for (int k0 = 0; k0 < K; k0 += 128) {
    for (int c = t; c < 2048; c += 256) {
      int row = c >> 5, k4 = (c & 31) * 4;
      float4 av = *(const float4*)&A[(size_t)(m0 + row) * K + k0 + k4];
      float rsv = rs ? rs[m0 + row] : 1.f;
      float vv[4] = { av.x, av.y, av.z, av.w };
      ushort4 hv, lv;
      u16* hp = (u16*)&hv; u16* lp = (u16*)&lv;
      #pragma unroll
      for (int j = 0; j < 4; j++) {
        float a = vv[j] * rsv * cwS[(k4 + j) & 127];
        u16 h = f2b(a);
        hp[j] = h;
        lp[j] = f2b(a - b2f(h));
      }
      *(ushort4*)&sAhi[row * 136 + k4] = hv;
      *(ushort4*)&sAlo[row * 136 + k4] = lv;
    }
    for (int c = t; c < 1024; c += 256) {
      int row = c >> 4, k8 = (c & 15) * 8;
      *(uint4*)&sBhi[row * 136 + k8] = *(const uint4*)&Bhi[(size_t)(n0 + row) * ldb + k0 + k8];
      *(uint4*)&sBlo[row * 136 + k8] = *(const uint4*)&Blo[(size_t)(n0 + row) * ldb + k0 + k8];
    }
    __syncthreads();
    #pragma unroll
    for (int ks = 0; ks < 4; ks++) {
      s16x8 ah[2], al[2], bh[2], bl[2];
      #pragma unroll
      for (int mr = 0; mr < 2; mr++) {
        int off = (wr * 32 + mr * 16 + l15) * 136 + ks * 32 + lg * 8;
        ah[mr] = *(const s16x8*)&sAhi[off];
        al[mr] = *(const s16x8*)&sAlo[off];
      }
      #pragma unroll
      for (int nr = 0; nr < 2; nr++) {
        int off = (wc * 32 + nr * 16 + l15) * 136 + ks * 32 + lg * 8;
        bh[nr] = *(const s16x8*)&sBhi[off];
        bl[nr] = *(const s16x8*)&sBlo[off];
      }
      #pragma unroll
      for (int mr = 0; mr < 2; mr++)
        #pragma unroll
        for (int nr = 0; nr < 2; nr++) {
          acc[mr][nr] = __builtin_amdgcn_mfma_f32_16x16x32_bf16(ah[mr], bh[nr], acc[mr][nr], 0, 0, 0);
          acc[mr][nr] = __builtin_amdgcn_mfma_f32_16x16x32_bf16(ah[mr], bl[nr], acc[mr][nr], 0, 0, 0);
          acc[mr][nr] = __builtin_amdgcn_mfma_f32_16x16x32_bf16(al[mr], bh[nr], acc[mr][nr], 0, 0, 0);
        }
    }
    __syncthreads();
  }

  #pragma unroll
  for (int mr = 0; mr < 2; mr++)
    #pragma unroll
    for (int nr = 0; nr < 2; nr++)
      #pragma unroll
      for (int r = 0; r < 4; r++) {
        int row = m0 + wr * 32 + mr * 16 + lg * 4 + r;
        int col = n0 + wc * 32 + nr * 16 + l15;
        size_t ix = (size_t)row * ldo + col;
        if (MODE == MB_RESID) O[ix] += acc[mr][nr][r];
        else                  O[ix]  = acc[mr][nr][r];
      }
}

// ---------------- fused bf3 gate+up+silu (layer 1) ----------------
// tile 64x64, K=128 in two 64-chunks (LDS 55KB -> 2 blocks/CU). Same 3-term
// mfma order per k as the separate kernels (bit-identical to round-4 values).
__global__ __launch_bounds__(256) void gemm_bf3_gu(
    const float* __restrict__ A, const float* __restrict__ rs, const float* __restrict__ cw,
    const u16* __restrict__ Gh, const u16* __restrict__ Gl,
    const u16* __restrict__ Uh, const u16* __restrict__ Ul,
    float* __restrict__ hh)
{
  __shared__ u16 sAh[64 * 72];
  __shared__ u16 sAl[64 * 72];
  __shared__ u16 sB[4][64 * 72];
  __shared__ float cwS[128];
  const int t = threadIdx.x;
  const int lane = t & 63;
  const int w = t >> 6;
  const int wr = w >> 1, wc = w & 1;
  const int m0 = blockIdx.x * 64;
  const int n0 = blockIdx.y * 64;
  const int l15 = lane & 15;
  const int lg  = lane >> 4;
  for (int i = t; i < 128; i += 256) cwS[i] = cw[i];
  __syncthreads();

  f32x4 aG[2][2] = {}, aU[2][2] = {};

  for (int k0 = 0; k0 < 128; k0 += 64) {
    for (int c = t; c < 1024; c += 256) {
      int row = c >> 4, k4 = (c & 15) * 4;
      float4 av = *(const float4*)&A[(size_t)(m0 + row) * 128 + k0 + k4];
      float rsv = rs[m0 + row];
      float vv[4] = { av.x, av.y, av.z, av.w };
      ushort4 hv, lv;
      u16* hp = (u16*)&hv; u16* lp = (u16*)&lv;
      #pragma unroll
      for (int j = 0; j < 4; j++) {
        float a = vv[j] * rsv * cwS[k0 + k4 + j];
        u16 h = f2b(a);
        hp[j] = h;
        lp[j] = f2b(a - b2f(h));
      }
      *(ushort4*)&sAh[row * 72 + k4] = hv;
      *(ushort4*)&sAl[row * 72 + k4] = lv;
    }
    for (int c = t; c < 2048; c += 256) {
      int which = c >> 9, cc = c & 511;
      int row = cc >> 3, k8 = (cc & 7) * 8;
      const u16* src = which == 0 ? Gh : which == 1 ? Gl : which == 2 ? Uh : Ul;
      *(uint4*)&sB[which][row * 72 + k8] = *(const uint4*)&src[(size_t)(n0 + row) * 128 + k0 + k8];
    }
    __syncthreads();
    #pragma unroll
    for (int ks = 0; ks < 2; ks++) {
      s16x8 ah[2], al[2];
      #pragma unroll
      for (int mr = 0; mr < 2; mr++) {
        int off = (wr * 32 + mr * 16 + l15) * 72 + ks * 32 + lg * 8;
        ah[mr] = *(const s16x8*)&sAh[off];
        al[mr] = *(const s16x8*)&sAl[off];
      }
      #pragma unroll
      for (int nr = 0; nr < 2; nr++) {
        int off = (wc * 32 + nr * 16 + l15) * 72 + ks * 32 + lg * 8;
        s16x8 gh = *(const s16x8*)&sB[0][off];
        s16x8 gl = *(const s16x8*)&sB[1][off];
        s16x8 uh = *(const s16x8*)&sB[2][off];
        s16x8 ul = *(const s16x8*)&sB[3][off];
        #pragma unroll
        for (int mr = 0; mr < 2; mr++) {
          aG[mr][nr] = __builtin_amdgcn_mfma_f32_16x16x32_bf16(ah[mr], gh, aG[mr][nr], 0, 0, 0);
          aG[mr][nr] = __builtin_amdgcn_mfma_f32_16x16x32_bf16(ah[mr], gl, aG[mr][nr], 0, 0, 0);
          aG[mr][nr] = __builtin_amdgcn_mfma_f32_16x16x32_bf16(al[mr], gh, aG[mr][nr], 0, 0, 0);
          aU[mr][nr] = __builtin_amdgcn_mfma_f32_16x16x32_bf16(ah[mr], uh, aU[mr][nr], 0, 0, 0);
          aU[mr][nr] = __builtin_amdgcn_mfma_f32_16x16x32_bf16(ah[mr], ul, aU[mr][nr], 0, 0, 0);
          aU[mr][nr] = __builtin_amdgcn_mfma_f32_16x16x32_bf16(al[mr], uh, aU[mr][nr], 0, 0, 0);
        }
      }
    }
    __syncthreads();
  }

  #pragma unroll
  for (int mr = 0; mr < 2; mr++)
    #pragma unroll
    for (int nr = 0; nr < 2; nr++)
      #pragma unroll
      for (int r = 0; r < 4; r++) {
        int row = m0 + wr * 32 + mr * 16 + lg * 4 + r;
        int col = n0 + wc * 32 + nr * 16 + l15;
        float g = aG[mr][nr][r], u = aU[mr][nr][r];
        hh[(size_t)row * 384 + col] = g / (1.f + expf(-g)) * u;
      }
}

// ---------------- selection pass 1 (unchanged) ----------------
__global__ __launch_bounds__(256) void sel_pass1(const float* __restrict__ kt,
    float* __restrict__ cV, int* __restrict__ cI)
{
  const int hb = blockIdx.y;
  const int h = hb >> 1;
  const float sgn = (hb & 1) ? -1.f : 1.f;
  const int wv = threadIdx.x >> 6;
  const int lane = threadIdx.x & 63;
  const int base = blockIdx.x * 8192 + wv * 2048;
  const float* row = kt + (size_t)h * NTOK;

  float vals[32];
  #pragma unroll
  for (int j4 = 0; j4 < 8; j4++) {
    float4 v4 = *(const float4*)&row[base + j4 * 256 + lane * 4];
    vals[j4 * 4 + 0] = sgn * v4.x; vals[j4 * 4 + 1] = sgn * v4.y;
    vals[j4 * 4 + 2] = sgn * v4.z; vals[j4 * 4 + 3] = sgn * v4.w;
  }
  float m = NEGINF; int mj = 0;
  #pragma unroll
  for (int j = 0; j < 32; j++) if (vals[j] > m) { m = vals[j]; mj = j; }

  unsigned int used = 0u;
  const size_t slot = (size_t)hb * 4096 + (blockIdx.x * 4 + wv) * 32;
  for (int r = 0; r < 32; r++) {
    float bv = m; int bl = lane; int bj = mj;
    #pragma unroll
    for (int off = 1; off < 64; off <<= 1) {
      float ov = __shfl_xor(bv, off, 64);
      int   ol = __shfl_xor(bl, off, 64);
      int   oj = __shfl_xor(bj, off, 64);
      if (ov > bv || (ov == bv && ol < bl)) { bv = ov; bl = ol; bj = oj; }
    }
    if (lane == 0) {
      cV[slot + r] = bv;
      cI[slot + r] = base + (bj >> 2) * 256 + bl * 4 + (bj & 3);
    }
    if (lane == bl) {
      used |= (1u << bj);
      m = NEGINF; mj = 0;
      #pragma unroll
      for (int j = 0; j < 32; j++)
        if (!((used >> j) & 1u) && vals[j] > m) { m = vals[j]; mj = j; }
    }
  }
}

// ---------------- selection pass 2 (epilogue now writes interleaved tabKV) ----------
__global__ __launch_bounds__(256) void sel_pass2(const float* __restrict__ cV,
    const int* __restrict__ cI, const float* __restrict__ x, const float* __restrict__ s,
    const float* __restrict__ nw, const float* __restrict__ Wv,
    float2* __restrict__ tabKV)
{
  __shared__ float lv[128];
  __shared__ int   li[128];
  __shared__ float selv[32];
  __shared__ int   seli[32];
  const int t = threadIdx.x;
  const int hb = blockIdx.x;
  const int h = hb >> 1;
  const int sb = hb & 1;
  const float sgn = sb ? -1.f : 1.f;
  const int wv = t >> 6;
  const int lane = t & 63;
  const size_t cb = (size_t)hb * 4096;

  float vals[16]; int idxs[16];
  #pragma unroll
  for (int j = 0; j < 16; j++) {
    vals[j] = cV[cb + t + j * 256];
    idxs[j] = cI[cb + t + j * 256];
  }
  float m = NEGINF; int mj = 0;
  #pragma unroll
  for (int j = 0; j < 16; j++) if (vals[j] > m) { m = vals[j]; mj = j; }

  unsigned int used = 0u;
  for (int r = 0; r < 32; r++) {
    float bv = m; int bl = lane; int bj = mj;
    #pragma unroll
    for (int off = 1; off < 64; off <<= 1) {
      float ov = __shfl_xor(bv, off, 64);
      int   ol = __shfl_xor(bl, off, 64);
      int   oj = __shfl_xor(bj, off, 64);
      if (ov > bv || (ov == bv && ol < bl)) { bv = ov; bl = ol; bj = oj; }
    }
    if (lane == 0) { lv[wv * 32 + r] = bv; li[wv * 32 + r] = 0; }
    if (lane == bl) {
      li[wv * 32 + r] = idxs[bj];
      used |= (1u << bj);
      m = NEGINF; mj = 0;
      #pragma unroll
      for (int j = 0; j < 16; j++)
        if (!((used >> j) & 1u) && vals[j] > m) { m = vals[j]; mj = j; }
    }
  }
  __syncthreads();

  if (t == 0) {
    int p[4] = {0, 0, 0, 0};
    for (int r = 0; r < 32; r++) {
      float best = NEGINF; int bw = 0;
      #pragma unroll
      for (int w = 0; w < 4; w++) {
        if (p[w] < 32) {
          float v = lv[w * 32 + p[w]];
          if (v > best) { best = v; bw = w; }
        }
      }
      selv[r] = best;
      seli[r] = li[bw * 32 + p[bw]];
      p[bw]++;
    }
  }
  __syncthreads();

  if (t < 32) {
    float kval = sgn * selv[t];
    int idx = seli[t];
    float acc = 0.f;
    const float* xr = &x[(size_t)idx * 128];
    const float* wvp = &Wv[h * 128];
    for (int k = 0; k < 128; k++) acc = fmaf(xr[k] * nw[k], wvp[k], acc);
    tabKV[(sb * 32 + t) * 128 + h] = make_float2(kval * LOG2E, acc * s[idx]);
  }
}

// ---------------- attention: float2 table, 2-token ILP ----------------
// RELAX=0 (layer 0): exp2f + exact div -> bit-identical to round 4.
// RELAX=1 (layer 1, post-discrete): raw v_exp_f32 + rcp.
template<int RELAX>
__global__ __launch_bounds__(512) void att_kernel(float* __restrict__ q,
    const float2* __restrict__ tabKV)
{
  __shared__ float2 tkv[8192];
  const int t = threadIdx.x;
  for (int i = t; i < 8192; i += 512) tkv[i] = tabKV[i];
  __syncthreads();
  const int h = t & 127;
  const int sub = t >> 7;
  const int base = blockIdx.x * 512;   // grid 512
  for (int it = 0; it < 64; it++) {
    const int tokA = base + it * 8 + sub;
    const size_t offA = (size_t)tokA * 128 + h;
    const size_t offB = offA + 512;    // tokA + 4
    const float qa = q[offA];
    const float qb = q[offB];
    const float2* ka = &tkv[(qa > 0.f ? 0 : 4096) + h];
    const float2* kb = &tkv[(qb > 0.f ? 0 : 4096) + h];
    float swa = 0.f, sva = 0.f, swb = 0.f, svb = 0.f;
    #pragma unroll
    for (int j = 0; j < 32; j++) {
      float2 A = ka[j * 128];
      float2 B = kb[j * 128];
      float ea = RELAX ? __builtin_amdgcn_exp2f(qa * A.x) : exp2f(qa * A.x);
      float eb = RELAX ? __builtin_amdgcn_exp2f(qb * B.x) : exp2f(qb * B.x);
      swa += ea; sva = fmaf(ea, A.y, sva);
      swb += eb; svb = fmaf(eb, B.y, svb);
    }
    if (RELAX) {
      q[offA] = sva * __builtin_amdgcn_rcpf(swa);
      q[offB] = svb * __builtin_amdgcn_rcpf(swb);
    } else {
      q[offA] = sva / swa;
      q[offB] = svb / swb;
    }
  }
}

// ---------------- host orchestration ----------------
// ws layout (bytes):
//   [0, 134217728)           x residual (f32)
//   [134217728, 268435456)   q (f32)
//   [268435456, 402653184)   kt / hh chunk scratch (<=100.7MB used)
//   [402653184, 403701760)   s per-token scales
//   [403701760, 403767296)   tabKV (float2[8192] = 64KB)
//   [403767296, 404160512)   whi arena; [404160512, 404553728) wlo arena
// sel candidate scratch (16.8 MB) lives in d_out (dead until final head).

extern "C" void kernel_launch(void* const* d_in, const int* in_sizes, int n_in,
                              void* d_out, int out_size, void* d_ws, size_t ws_size,
                              hipStream_t stream)
{
  (void)in_sizes; (void)n_in; (void)out_size; (void)ws_size;
  const int*   bytes = (const int*)d_in[0];
  const float* be    = (const float*)d_in[1];
  const float* bpe   = (const float*)d_in[2];
  const float* lpe   = (const float*)d_in[3];
  const float* Wq    = (const float*)d_in[4];
  const float* Wk    = (const float*)d_in[5];
  const float* Wv    = (const float*)d_in[6];
  const float* Wo    = (const float*)d_in[7];
  const float* n1w   = (const float*)d_in[8];
  const float* n2w   = (const float*)d_in[9];
  const float* wg    = (const float*)d_in[10];
  const float* wu    = (const float*)d_in[11];
  const float* wd    = (const float*)d_in[12];
  const float* fnw   = (const float*)d_in[13];
  const float* outw  = (const float*)d_in[14];
  float* out = (float*)d_out;

  char* ws = (char*)d_ws;
  float*  x     = (float*)(ws + 0);
  float*  q     = (float*)(ws + 134217728);
  float*  kt    = (float*)(ws + 268435456);
  float*  s     = (float*)(ws + 402653184);
  float2* tabKV = (float2*)(ws + 403701760);
  u16*    whi   = (u16*)(ws + 403767296);
  u16*    wlo   = (u16*)(ws + 404160512);
  float*  hh    = kt;                     // MLP scratch aliases kt (dead after sel)
  float*  cV    = out;
  int*    cI    = (int*)(out + 256 * 4096);

  const size_t AG = 0, AU = 49152, AD = 98304, AW = 147456, AH = 163840;

  prep_split<<<768, 256, 0, stream>>>(wg, wu, wd, Wo, outw, whi, wlo);
  embed_kernel<<<32768, 256, 0, stream>>>(bytes, be, bpe, lpe, x);

  for (int l = 0; l < 2; l++) {
    const float* wq = Wq + l * 16384;
    const float* wk = Wk + l * 16384;
    const float* wv = Wv + l * 16384;
    const float* wo = Wo + l * 16384;
    const float* g1 = n1w + l * 128;
    const float* g2 = n2w + l * 128;
    const float* wgl = wg + l * 43648;
    const float* wul = wu + l * 43648;
    const float* wdl = wd + l * 43648;

    scale_kernel<<<1024, 256, 0, stream>>>(x, s);
    gemm_f32<M32_QK><<<dim3(4096, 2), 256, 0, stream>>>(
        x, s, g1, wq, wk, 128, 128, 128, 128, q, kt, 128);
    sel_pass1<<<dim3(32, 256), 256, 0, stream>>>(kt, cV, cI);
    sel_pass2<<<256, 256, 0, stream>>>(cV, cI, x, s, g1, wv, tabKV);

    if (l == 0) {
      att_kernel<0><<<512, 512, 0, stream>>>(q, tabKV);
      gemm_f32<M32_RESID><<<dim3(4096, 1), 256, 0, stream>>>(
          q, nullptr, nullptr, wo, nullptr, 128, 128, 128, 128, x, nullptr, 128);
      scale_kernel<<<1024, 256, 0, stream>>>(x, s);
      for (int c = 0; c < 4; c++) {
        const size_t base = (size_t)c * 65536;
        gemm_f32_gu<<<dim3(1024, 6), 256, 0, stream>>>(
            x + base * 128, s + base, g2, wgl, wul, hh);
        gemm_f32<M32_RESID><<<dim3(1024, 1), 256, 0, stream>>>(
            hh, nullptr, nullptr, wdl, nullptr, 384, 341, 128, 341,
            x + base * 128, nullptr, 128);
      }
    } else {
      att_kernel<1><<<512, 512, 0, stream>>>(q, tabKV);
      gemm_bf3<MB_RESID><<<dim3(4096, 2), 256, 0, stream>>>(
          q, nullptr, nullptr, 128, whi + AW, wlo + AW, 128, x, 128);
      scale_kernel<<<1024, 256, 0, stream>>>(x, s);
      for (int c = 0; c < 4; c++) {
        const size_t base = (size_t)c * 65536;
        gemm_bf3_gu<<<dim3(1024, 6), 256, 0, stream>>>(
            x + base * 128, s + base, g2,
            whi + AG, wlo + AG, whi + AU, wlo + AU, hh);
        gemm_bf3<MB_RESID><<<dim3(1024, 2), 256, 0, stream>>>(
            hh, nullptr, nullptr, 384, whi + AD, wlo + AD, 384, x + base * 128, 128);
      }
    }
  }

  scale_kernel<<<1024, 256, 0, stream>>>(x, s);
  gemm_bf3<MB_RAW><<<dim3(4096, 4), 256, 0, stream>>>(
      x, s, fnw, 128, whi + AH, wlo + AH, 128, out, 256);
}